// Round 10
// baseline (318.950 us; speedup 1.0000x reference)
//
#include <hip/hip_runtime.h>

// Problem constants (B=32, N=256, D=256 -> M=8192)
#define M_ROWS 8192
#define D_DIM  256
#define TOTB   2048               // gemm blocks (4 wave-jobs each)
#define NRED   64                 // tail reducer blocks

// Fold 1/TEMP * log2(e) into normalization: acc = log2(e)*sim/TEMP, e = exp2(acc)
#define ALPHA  4.53982478f        // sqrt(log2(e)/0.07)

// fp8 fragment-order layout:
//   8-B chunk index = tile16 * 512 + k32 * 64 + lane,   lane = quad*16 + l16
//   chunk contents  = row (tile16*16 + l16), k = k32*32 + quad*8 .. +7  (8 x e4m3)
// => an MFMA A/B fragment load (16x16x32_fp8) is 64 lanes x 8 B fully contiguous.

typedef __attribute__((ext_vector_type(4))) float  floatx4;  // MFMA C/D

__device__ inline unsigned short f2bf(float f) {
    union { float f; unsigned int u; } v; v.f = f;
    unsigned int u = v.u;
    u = (u + 0x7fffu + ((u >> 16) & 1u)) >> 16;   // RNE
    return (unsigned short)u;
}

__device__ inline float bf2f(unsigned short b) {
    union { unsigned int u; float f; } v; v.u = (unsigned int)b << 16;
    return v.f;
}

__device__ inline float fast_exp2(float x) {
#if __has_builtin(__builtin_amdgcn_exp2f)
    return __builtin_amdgcn_exp2f(x);
#else
    return exp2f(x);
#endif
}

// Kernel 1: L2-normalize 16 rows per block, scale by ALPHA, emit fp8 e4m3 in
// fragment order via padded LDS transpose. Block 0 zeroes glob:
// [0..3]=sums, int[4]=counter1, int[5]=flag, int[6]=counter2.
__global__ __launch_bounds__(256) void normalize_kernel(
    const float* __restrict__ af, const float* __restrict__ vf,
    unsigned char* __restrict__ aB, unsigned char* __restrict__ vB,
    float* __restrict__ glob)
{
    __shared__ unsigned short tileS[16 * 264];   // 8.25 KB

    if (blockIdx.x == 0) {
        if (threadIdx.x < 4) glob[threadIdx.x] = 0.f;
        if (threadIdx.x >= 4 && threadIdx.x < 7) ((int*)glob)[threadIdx.x] = 0;
    }

    const int b = blockIdx.x;            // 0..1023
    const bool isA = b < 512;
    const int T = isA ? b : b - 512;     // tile16 index 0..511
    const float* src = (isA ? af : vf) + (size_t)T * 16 * D_DIM;
    unsigned char* dst = (isA ? aB : vB) + (size_t)T * 4096;  // 512 chunks x 8 B

    const int t = threadIdx.x;
    const int row = t >> 4, c = t & 15;  // 16 threads per row, 16 elems each

    const float* p = src + row * D_DIM + c * 16;
    float4 x0 = ((const float4*)p)[0], x1 = ((const float4*)p)[1];
    float4 x2 = ((const float4*)p)[2], x3 = ((const float4*)p)[3];
    float ss = x0.x*x0.x + x0.y*x0.y + x0.z*x0.z + x0.w*x0.w
             + x1.x*x1.x + x1.y*x1.y + x1.z*x1.z + x1.w*x1.w
             + x2.x*x2.x + x2.y*x2.y + x2.z*x2.z + x2.w*x2.w
             + x3.x*x3.x + x3.y*x3.y + x3.z*x3.z + x3.w*x3.w;
    #pragma unroll
    for (int m = 1; m < 16; m <<= 1) ss += __shfl_xor(ss, m, 64);
    float scale = ALPHA / fmaxf(sqrtf(ss), 1e-12f);

    unsigned short* q = tileS + row * 264 + c * 16;
    ushort4 o0, o1, o2, o3;
    o0.x = f2bf(x0.x*scale); o0.y = f2bf(x0.y*scale); o0.z = f2bf(x0.z*scale); o0.w = f2bf(x0.w*scale);
    o1.x = f2bf(x1.x*scale); o1.y = f2bf(x1.y*scale); o1.z = f2bf(x1.z*scale); o1.w = f2bf(x1.w*scale);
    o2.x = f2bf(x2.x*scale); o2.y = f2bf(x2.y*scale); o2.z = f2bf(x2.z*scale); o2.w = f2bf(x2.w*scale);
    o3.x = f2bf(x3.x*scale); o3.y = f2bf(x3.y*scale); o3.z = f2bf(x3.z*scale); o3.w = f2bf(x3.w*scale);
    ((ushort4*)q)[0] = o0; ((ushort4*)q)[1] = o1;
    ((ushort4*)q)[2] = o2; ((ushort4*)q)[3] = o3;
    __syncthreads();

    #pragma unroll
    for (int s = 0; s < 2; ++s) {
        const int ch  = t + s * 256;             // 0..511
        const int l16 = ch & 15, quad = (ch >> 4) & 3, k32 = ch >> 6;
        const unsigned short* rp = &tileS[l16 * 264 + k32 * 32 + quad * 8];
        float f0 = bf2f(rp[0]), f1 = bf2f(rp[1]), f2 = bf2f(rp[2]), f3 = bf2f(rp[3]);
        float f4 = bf2f(rp[4]), f5 = bf2f(rp[5]), f6 = bf2f(rp[6]), f7 = bf2f(rp[7]);
        int p0 = __builtin_amdgcn_cvt_pk_fp8_f32(f0, f1, 0, false);
        p0     = __builtin_amdgcn_cvt_pk_fp8_f32(f2, f3, p0, true);
        int p1 = __builtin_amdgcn_cvt_pk_fp8_f32(f4, f5, 0, false);
        p1     = __builtin_amdgcn_cvt_pk_fp8_f32(f6, f7, p1, true);
        int2 outv; outv.x = p0; outv.y = p1;
        *(int2*)(dst + (size_t)ch * 8) = outv;
    }
}

// Kernel 2: barrier-free wave-job GEMM + exp2 + partials + distributed tail.
// Wave-job = 64 rows x 128 cols as TWO sequential 32-row passes (acc[2][8],
// B-frags re-read from L1). Waves fully independent (no __syncthreads in hot
// path) => the 3 waves/SIMD desync into natural MFMA<->VALU interleave.
// rowPart[by][i][2] and colPart[bx64][j][2] slices are wave-exclusive.
// Tail: last 64 blocks (device counter) reduce partials + emit the scalar.
__global__ __launch_bounds__(256, 3) void gemm_loss_kernel(
    const unsigned char* __restrict__ aB, const unsigned char* __restrict__ vB,
    const int* __restrict__ la, const int* __restrict__ lv,
    float* __restrict__ rowPart, float* __restrict__ colPart,
    float* __restrict__ glob, float* __restrict__ out)
{
    const int tid  = threadIdx.x;
    const int wave = tid >> 6, lane = tid & 63;
    const int quad = lane >> 4, l16 = lane & 15;

    const int job  = blockIdx.x * 4 + wave;     // 0..8191
    const int by   = job >> 7;                  // 0..63  (j-tile, 128 cols)
    const int bx64 = job & 127;                 // 0..127 (i-slab, 64 rows)
    const int i0 = bx64 * 64, j0 = by * 128;

    // fragment bases: tile16 stride = 4096 B; k32 stride = 512 B
    const unsigned char* Abase = aB + ((size_t)(bx64 * 4) * 512 + lane) * 8;
    const unsigned char* Vbase = vB + ((size_t)(by * 8) * 512 + lane) * 8;

    float mvf[8];
    #pragma unroll
    for (int jt = 0; jt < 8; ++jt)
        mvf[jt] = (float)lv[j0 + jt * 16 + l16];

    float cT[8] = {}, c1[8] = {};

    #pragma unroll
    for (int pass = 0; pass < 2; ++pass) {
        const unsigned char* Ap = Abase + (size_t)pass * 2 * 4096;
        floatx4 acc[2][8] = {};
        long long afr[2][2], bfr[2][8];

        #pragma unroll
        for (int it = 0; it < 2; ++it) afr[0][it] = *(const long long*)(Ap + it * 4096);
        #pragma unroll
        for (int jt = 0; jt < 8; ++jt) bfr[0][jt] = *(const long long*)(Vbase + jt * 4096);

        #pragma unroll
        for (int k32 = 0; k32 < 8; ++k32) {     // 8 MFMA K=32 steps (K=256)
            const int cur = k32 & 1, nxt = cur ^ 1;
            if (k32 < 7) {
                const size_t ko = (size_t)(k32 + 1) * 512;
                #pragma unroll
                for (int it = 0; it < 2; ++it)
                    afr[nxt][it] = *(const long long*)(Ap + it * 4096 + ko);
                #pragma unroll
                for (int jt = 0; jt < 8; ++jt)
                    bfr[nxt][jt] = *(const long long*)(Vbase + jt * 4096 + ko);
            }
            #pragma unroll
            for (int it = 0; it < 2; ++it)
                #pragma unroll
                for (int jt = 0; jt < 8; ++jt)
                    acc[it][jt] = __builtin_amdgcn_mfma_f32_16x16x32_fp8_fp8(
                        afr[cur][it], bfr[cur][jt], acc[it][jt], 0, 0, 0);
        }

        // epilogue for this pass's 32 rows; C/D: col = l16, row = quad*4 + r
        float maf[2][4];
        #pragma unroll
        for (int it = 0; it < 2; ++it)
            #pragma unroll
            for (int r = 0; r < 4; ++r)
                maf[it][r] = (float)la[i0 + pass * 32 + it * 16 + quad * 4 + r];

        float rT[2][4] = {}, r1[2][4] = {};
        #pragma unroll
        for (int it = 0; it < 2; ++it) {
            #pragma unroll
            for (int jt = 0; jt < 8; ++jt) {
                #pragma unroll
                for (int r = 0; r < 4; ++r) {
                    float e = fast_exp2(acc[it][jt][r]);
                    rT[it][r] += e;
                    r1[it][r] = fmaf(mvf[jt], e, r1[it][r]);
                    cT[jt] += e;
                    c1[jt] = fmaf(maf[it][r], e, c1[jt]);
                }
            }
        }

        // row sums: reduce over the 16 lanes of the quad, direct store
        #pragma unroll
        for (int it = 0; it < 2; ++it) {
            #pragma unroll
            for (int r = 0; r < 4; ++r) {
                float s0 = rT[it][r], s1 = r1[it][r];
                #pragma unroll
                for (int m = 1; m < 16; m <<= 1) {
                    s0 += __shfl_xor(s0, m, 64);
                    s1 += __shfl_xor(s1, m, 64);
                }
                if (l16 == 0) {
                    int rowg = i0 + pass * 32 + it * 16 + quad * 4 + r;
                    float2 v2; v2.x = s0; v2.y = s1;
                    *(float2*)&rowPart[((size_t)by * M_ROWS + rowg) * 2] = v2;
                }
            }
        }
    }

    // col sums: reduce over quads (register-only), direct store
    #pragma unroll
    for (int jt = 0; jt < 8; ++jt) {
        float t0 = cT[jt], t1 = c1[jt];
        t0 += __shfl_xor(t0, 16, 64); t0 += __shfl_xor(t0, 32, 64);
        t1 += __shfl_xor(t1, 16, 64); t1 += __shfl_xor(t1, 32, 64);
        if (quad == 0) {
            float2 v2; v2.x = t0; v2.y = t1;
            *(float2*)&colPart[((size_t)bx64 * M_ROWS + j0 + jt * 16 + l16) * 2] = v2;
        }
    }

    // ---- completion protocol + distributed tail reduce ----
    __shared__ int sRank;
    __shared__ float red[4][2];
    __syncthreads();                   // all 4 waves' stores issued
    if (tid == 0) {
        __threadfence();               // make this block's partials device-visible
        int old = atomicAdd((int*)glob + 4, 1);
        sRank = old - (TOTB - NRED);   // >=0 -> this block is a reducer
        if (old == TOTB - 1) {
            __threadfence();
            __hip_atomic_store((int*)glob + 5, 1, __ATOMIC_RELEASE, __HIP_MEMORY_SCOPE_AGENT);
        }
    }
    __syncthreads();
    const int rank = sRank;
    if (rank < 0) return;

    if (tid == 0 && rank != NRED - 1) {
        while (__hip_atomic_load((int*)glob + 5, __ATOMIC_ACQUIRE, __HIP_MEMORY_SCOPE_AGENT) == 0)
            __builtin_amdgcn_s_sleep(2);
    }
    __syncthreads();
    __threadfence();                   // acquire: see all blocks' partial writes

    const bool aside = rank < 32;
    const int idx = (aside ? rank : rank - 32) * 256 + tid;   // row or col index
    const float* part = aside ? rowPart : colPart;
    const int* lab = aside ? la : lv;
    const int nb = aside ? 64 : 128;

    float tot = 0.f, cc1 = 0.f;
    #pragma unroll 4
    for (int b = 0; b < nb; ++b) {
        float2 p = *(const float2*)(part + ((size_t)b * M_ROWS + idx) * 2);
        tot += p.x; cc1 += p.y;
    }
    float num = lab[idx] ? cc1 : 0.1f * (tot - cc1);
    float lg = 0.f, cnt = 0.f;
    if (num > 0.f) { lg = logf((num + 1e-8f) / (tot + 1e-8f)); cnt = 1.f; }

    #pragma unroll
    for (int m = 1; m < 64; m <<= 1) {
        lg  += __shfl_xor(lg,  m, 64);
        cnt += __shfl_xor(cnt, m, 64);
    }
    if (lane == 0) { red[wave][0] = lg; red[wave][1] = cnt; }
    __syncthreads();
    if (tid == 0) {
        float slg  = red[0][0] + red[1][0] + red[2][0] + red[3][0];
        float scnt = red[0][1] + red[1][1] + red[2][1] + red[3][1];
        float* base = glob + (aside ? 0 : 2);
        atomicAdd(&base[0], slg);
        atomicAdd(&base[1], scnt);
        __threadfence();
        int old2 = atomicAdd((int*)glob + 6, 1);
        if (old2 == NRED - 1) {
            __threadfence();
            float sA = atomicAdd(&glob[0], 0.f);
            float cA = atomicAdd(&glob[1], 0.f);
            float sV = atomicAdd(&glob[2], 0.f);
            float cV = atomicAdd(&glob[3], 0.f);
            float lossA = -sA / fmaxf(cA, 1.f);
            float lossV = -sV / fmaxf(cV, 1.f);
            out[0] = 0.5f * (lossA + lossV);
        }
    }
}

extern "C" void kernel_launch(void* const* d_in, const int* in_sizes, int n_in,
                              void* d_out, int out_size, void* d_ws, size_t ws_size,
                              hipStream_t stream)
{
    const float* af = (const float*)d_in[0];
    const float* vf = (const float*)d_in[1];
    const int*   la = (const int*)d_in[2];
    const int*   lv = (const int*)d_in[3];
    float* out = (float*)d_out;

    char* ws = (char*)d_ws;
    unsigned char* aB = (unsigned char*)ws;                            // 2 MiB (fp8 fragment order)
    unsigned char* vB = (unsigned char*)(ws + 2ull * 1024 * 1024);     // 2 MiB
    float* rowPart   = (float*)(ws +  4ull * 1024 * 1024);             // 4 MiB [64][8192][2]
    float* colPart   = (float*)(ws +  8ull * 1024 * 1024);             // 8 MiB [128][8192][2]
    float* glob      = (float*)(ws + 16ull * 1024 * 1024);             // sums + counters

    normalize_kernel<<<1024, 256, 0, stream>>>(af, vf, aB, vB, glob);
    gemm_loss_kernel<<<TOTB, 256, 0, stream>>>(aB, vB, la, lv, rowPart, colPart, glob, out);
}

// Round 11
// 285.446 us; speedup vs baseline: 1.1174x; 1.1174x over previous
//
#include <hip/hip_runtime.h>

// Problem constants (B=32, N=256, D=256 -> M=8192)
#define M_ROWS 8192
#define D_DIM  256
#define TOTB   4096               // gemm blocks (128x128 tile each)
#define NRED   64                 // tail reducer blocks

// Fold 1/TEMP * log2(e) into normalization: acc = log2(e)*sim/TEMP, e = exp2(acc)
#define ALPHA  4.53982478f        // sqrt(log2(e)/0.07)

// MX fp8 fragment-order layout (for mfma_scale 16x16x128):
//   per (tile16, kb) fragment = 2048 B: lane (quad*16+l16) holds 32 B =
//   row (tile16*16 + l16), k = kb*128 + quad*32 + [0..31]   (32 x e4m3)
//   tile16 stride = 4096 B (2 kb blocks); full matrix = 512 tiles = 2 MiB.

typedef __attribute__((ext_vector_type(4))) float  floatx4;  // MFMA C/D
typedef __attribute__((ext_vector_type(8))) int    intx8;    // MFMA A/B (32 B)

__device__ inline unsigned short f2bf(float f) {
    union { float f; unsigned int u; } v; v.f = f;
    unsigned int u = v.u;
    u = (u + 0x7fffu + ((u >> 16) & 1u)) >> 16;   // RNE
    return (unsigned short)u;
}

__device__ inline float bf2f(unsigned short b) {
    union { unsigned int u; float f; } v; v.u = (unsigned int)b << 16;
    return v.f;
}

__device__ inline float fast_exp2(float x) {
#if __has_builtin(__builtin_amdgcn_exp2f)
    return __builtin_amdgcn_exp2f(x);
#else
    return exp2f(x);
#endif
}

// Kernel 1: L2-normalize 16 rows per block, scale by ALPHA, emit fp8 e4m3 in
// MX fragment order via padded LDS transpose. Block 0 zeroes glob:
// [0..3]=sums, int[4]=counter1, int[5]=flag, int[6]=counter2.
__global__ __launch_bounds__(256) void normalize_kernel(
    const float* __restrict__ af, const float* __restrict__ vf,
    unsigned char* __restrict__ aB, unsigned char* __restrict__ vB,
    float* __restrict__ glob)
{
    __shared__ unsigned short tileS[16 * 264];   // 8.25 KB

    if (blockIdx.x == 0) {
        if (threadIdx.x < 4) glob[threadIdx.x] = 0.f;
        if (threadIdx.x >= 4 && threadIdx.x < 7) ((int*)glob)[threadIdx.x] = 0;
    }

    const int b = blockIdx.x;            // 0..1023
    const bool isA = b < 512;
    const int T = isA ? b : b - 512;     // tile16 index 0..511
    const float* src = (isA ? af : vf) + (size_t)T * 16 * D_DIM;
    unsigned char* dst = (isA ? aB : vB) + (size_t)T * 4096;

    const int t = threadIdx.x;
    const int row = t >> 4, c = t & 15;  // 16 threads per row, 16 elems each

    const float* p = src + row * D_DIM + c * 16;
    float4 x0 = ((const float4*)p)[0], x1 = ((const float4*)p)[1];
    float4 x2 = ((const float4*)p)[2], x3 = ((const float4*)p)[3];
    float ss = x0.x*x0.x + x0.y*x0.y + x0.z*x0.z + x0.w*x0.w
             + x1.x*x1.x + x1.y*x1.y + x1.z*x1.z + x1.w*x1.w
             + x2.x*x2.x + x2.y*x2.y + x2.z*x2.z + x2.w*x2.w
             + x3.x*x3.x + x3.y*x3.y + x3.z*x3.z + x3.w*x3.w;
    #pragma unroll
    for (int m = 1; m < 16; m <<= 1) ss += __shfl_xor(ss, m, 64);
    float scale = ALPHA / fmaxf(sqrtf(ss), 1e-12f);

    unsigned short* q = tileS + row * 264 + c * 16;
    ushort4 o0, o1, o2, o3;
    o0.x = f2bf(x0.x*scale); o0.y = f2bf(x0.y*scale); o0.z = f2bf(x0.z*scale); o0.w = f2bf(x0.w*scale);
    o1.x = f2bf(x1.x*scale); o1.y = f2bf(x1.y*scale); o1.z = f2bf(x1.z*scale); o1.w = f2bf(x1.w*scale);
    o2.x = f2bf(x2.x*scale); o2.y = f2bf(x2.y*scale); o2.z = f2bf(x2.z*scale); o2.w = f2bf(x2.w*scale);
    o3.x = f2bf(x3.x*scale); o3.y = f2bf(x3.y*scale); o3.z = f2bf(x3.z*scale); o3.w = f2bf(x3.w*scale);
    ((ushort4*)q)[0] = o0; ((ushort4*)q)[1] = o1;
    ((ushort4*)q)[2] = o2; ((ushort4*)q)[3] = o3;
    __syncthreads();

    // phase 2: thread t emits 16 B of the MX fragment layout (byte off = t*16):
    // kb = t>>7, r = t&127, lane = r>>1, half = r&1;
    // source = LDS row (lane&15), k = kb*128 + (lane>>4)*32 + half*16 .. +15
    {
        const int kb = t >> 7, r = t & 127;
        const int ln = r >> 1, half = r & 1;
        const int quad = ln >> 4, l16 = ln & 15;
        const unsigned short* rp = &tileS[l16 * 264 + kb * 128 + quad * 32 + half * 16];
        int4 outv;
        int* op = (int*)&outv;
        #pragma unroll
        for (int g = 0; g < 4; ++g) {
            float f0 = bf2f(rp[g*4+0]), f1 = bf2f(rp[g*4+1]);
            float f2 = bf2f(rp[g*4+2]), f3 = bf2f(rp[g*4+3]);
            int pk = __builtin_amdgcn_cvt_pk_fp8_f32(f0, f1, 0, false);
            pk     = __builtin_amdgcn_cvt_pk_fp8_f32(f2, f3, pk, true);
            op[g] = pk;
        }
        *(int4*)(dst + (size_t)t * 16) = outv;
    }
}

// Kernel 2: MX fp8 GEMM (acc = log2e*sim/T) + exp2 + (total,class1) partials
// + distributed tail reduce (last-64-blocks protocol; no reduce dispatch).
// Block 256 = 4 waves; block tile 128x128 (R9's proven supertile swizzle);
// wave quadrant 64x64: acc[4][4] (64 AGPR), 2 K=128 steps, unit E8M0 scales.
__global__ __launch_bounds__(256, 3) void gemm_loss_kernel(
    const unsigned char* __restrict__ aB, const unsigned char* __restrict__ vB,
    const int* __restrict__ la, const int* __restrict__ lv,
    float* __restrict__ rowPart, float* __restrict__ colPart,
    float* __restrict__ glob, float* __restrict__ out)
{
    const int tid  = threadIdx.x;
    const int wave = tid >> 6, lane = tid & 63;
    const int quad = lane >> 4, l16 = lane & 15;
    const int rowhalf = wave >> 1, colhalf = wave & 1;

    // supertile swizzle: 16 supers x 256 inner -> 16x16 tile regions (L2 locality)
    const int super = blockIdx.x >> 8;          // 0..15
    const int inner = blockIdx.x & 255;
    const int bx = (super & 3) * 16 + (inner & 15);    // 0..63 (i-tile)
    const int by = (super >> 2) * 16 + (inner >> 4);   // 0..63 (j-tile)
    const int i0 = bx * 128, j0 = by * 128;

    // fragment bases: tile16 stride 4096 B, kb stride 2048 B, lane*32 B
    const unsigned char* Abase = aB + (size_t)(bx * 8 + rowhalf * 4) * 4096 + (size_t)lane * 32;
    const unsigned char* Vbase = vB + (size_t)(by * 8 + colhalf * 4) * 4096 + (size_t)lane * 32;

    floatx4 acc[4][4] = {};

    #pragma unroll
    for (int kb = 0; kb < 2; ++kb) {            // two K=128 steps (K=256)
        intx8 afr[4], bfr[4];
        #pragma unroll
        for (int it = 0; it < 4; ++it) {
            const unsigned char* p = Abase + it * 4096 + kb * 2048;
            ((int4*)&afr[it])[0] = *(const int4*)p;
            ((int4*)&afr[it])[1] = *(const int4*)(p + 16);
        }
        #pragma unroll
        for (int jt = 0; jt < 4; ++jt) {
            const unsigned char* p = Vbase + jt * 4096 + kb * 2048;
            ((int4*)&bfr[jt])[0] = *(const int4*)p;
            ((int4*)&bfr[jt])[1] = *(const int4*)(p + 16);
        }
        #pragma unroll
        for (int it = 0; it < 4; ++it)
            #pragma unroll
            for (int jt = 0; jt < 4; ++jt)
                acc[it][jt] = __builtin_amdgcn_mfma_scale_f32_16x16x128_f8f6f4(
                    afr[it], bfr[jt], acc[it][jt],
                    0 /*cbsz: fp8*/, 0 /*blgp: fp8*/,
                    0, 0x7f7f7f7f,   /* scale A = 1.0 (E8M0 127) */
                    0, 0x7f7f7f7f);  /* scale B = 1.0 */
    }

    // ---- epilogue: exp2 + (total, class1); C/D: col = l16, row = quad*4 + r
    float maf[4][4];
    #pragma unroll
    for (int it = 0; it < 4; ++it)
        #pragma unroll
        for (int r = 0; r < 4; ++r)
            maf[it][r] = (float)la[i0 + rowhalf * 64 + it * 16 + quad * 4 + r];
    float mvf[4];
    #pragma unroll
    for (int jt = 0; jt < 4; ++jt)
        mvf[jt] = (float)lv[j0 + colhalf * 64 + jt * 16 + l16];

    float rT[4][4] = {}, r1[4][4] = {};
    float cT[4] = {}, c1[4] = {};
    #pragma unroll
    for (int it = 0; it < 4; ++it) {
        #pragma unroll
        for (int jt = 0; jt < 4; ++jt) {
            #pragma unroll
            for (int r = 0; r < 4; ++r) {
                float e = fast_exp2(acc[it][jt][r]);
                rT[it][r] += e;
                r1[it][r] = fmaf(mvf[jt], e, r1[it][r]);
                cT[jt] += e;
                c1[jt] = fmaf(maf[it][r], e, c1[jt]);
            }
        }
    }

    __shared__ float rowS[2][128][2];   // [colhalf][row][cls] 2 KB
    __shared__ float colS[2][128][2];   // [rowhalf][col][cls] 2 KB

    // row sums: reduce over the quad's 16 lanes, stage per col-half
    #pragma unroll
    for (int it = 0; it < 4; ++it) {
        #pragma unroll
        for (int r = 0; r < 4; ++r) {
            float s0 = rT[it][r], s1 = r1[it][r];
            #pragma unroll
            for (int m = 1; m < 16; m <<= 1) {
                s0 += __shfl_xor(s0, m, 64);
                s1 += __shfl_xor(s1, m, 64);
            }
            if (l16 == 0) {
                int rl = rowhalf * 64 + it * 16 + quad * 4 + r;   // 0..127
                rowS[colhalf][rl][0] = s0;
                rowS[colhalf][rl][1] = s1;
            }
        }
    }
    // col sums: reduce over quads (register-only), stage per row-half
    #pragma unroll
    for (int jt = 0; jt < 4; ++jt) {
        float t0 = cT[jt], t1 = c1[jt];
        t0 += __shfl_xor(t0, 16, 64); t0 += __shfl_xor(t0, 32, 64);
        t1 += __shfl_xor(t1, 16, 64); t1 += __shfl_xor(t1, 32, 64);
        if (quad == 0) {
            int cl = colhalf * 64 + jt * 16 + l16;                // 0..127
            colS[rowhalf][cl][0] = t0;
            colS[rowhalf][cl][1] = t1;
        }
    }
    __syncthreads();

    // combine halves, coalesced per-block partial writes (256 floats each)
    {
        const int rl  = tid >> 1;      // 0..127
        const int cls = tid & 1;
        rowPart[((size_t)by * M_ROWS + i0 + rl) * 2 + cls] =
            rowS[0][rl][cls] + rowS[1][rl][cls];
        colPart[((size_t)bx * M_ROWS + j0 + rl) * 2 + cls] =
            colS[0][rl][cls] + colS[1][rl][cls];
    }

    // ---- completion protocol + distributed tail reduce ----
    __shared__ int sRank;
    __shared__ float red[4][2];
    if (tid == 0) {
        __threadfence();               // make this block's partials device-visible
        int old = atomicAdd((int*)glob + 4, 1);
        sRank = old - (TOTB - NRED);   // >=0 -> this block is a reducer
        if (old == TOTB - 1) {
            __threadfence();
            __hip_atomic_store((int*)glob + 5, 1, __ATOMIC_RELEASE, __HIP_MEMORY_SCOPE_AGENT);
        }
    }
    __syncthreads();
    const int rank = sRank;
    if (rank < 0) return;

    if (tid == 0 && rank != NRED - 1) {
        while (__hip_atomic_load((int*)glob + 5, __ATOMIC_ACQUIRE, __HIP_MEMORY_SCOPE_AGENT) == 0)
            __builtin_amdgcn_s_sleep(2);
    }
    __syncthreads();
    __threadfence();                   // acquire: see all blocks' partial writes

    const bool aside = rank < 32;
    const int idx = (aside ? rank : rank - 32) * 256 + tid;   // row or col index
    const float* part = aside ? rowPart : colPart;
    const int* lab = aside ? la : lv;

    float tot = 0.f, cc1 = 0.f;
    #pragma unroll 4
    for (int b = 0; b < 64; ++b) {
        float2 p = *(const float2*)(part + ((size_t)b * M_ROWS + idx) * 2);
        tot += p.x; cc1 += p.y;
    }
    float num = lab[idx] ? cc1 : 0.1f * (tot - cc1);
    float lg = 0.f, cnt = 0.f;
    if (num > 0.f) { lg = logf((num + 1e-8f) / (tot + 1e-8f)); cnt = 1.f; }

    #pragma unroll
    for (int m = 1; m < 64; m <<= 1) {
        lg  += __shfl_xor(lg,  m, 64);
        cnt += __shfl_xor(cnt, m, 64);
    }
    if (lane == 0) { red[wave][0] = lg; red[wave][1] = cnt; }
    __syncthreads();
    if (tid == 0) {
        float slg  = red[0][0] + red[1][0] + red[2][0] + red[3][0];
        float scnt = red[0][1] + red[1][1] + red[2][1] + red[3][1];
        float* base = glob + (aside ? 0 : 2);
        atomicAdd(&base[0], slg);
        atomicAdd(&base[1], scnt);
        __threadfence();
        int old2 = atomicAdd((int*)glob + 6, 1);
        if (old2 == NRED - 1) {
            __threadfence();
            float sA = atomicAdd(&glob[0], 0.f);
            float cA = atomicAdd(&glob[1], 0.f);
            float sV = atomicAdd(&glob[2], 0.f);
            float cV = atomicAdd(&glob[3], 0.f);
            float lossA = -sA / fmaxf(cA, 1.f);
            float lossV = -sV / fmaxf(cV, 1.f);
            out[0] = 0.5f * (lossA + lossV);
        }
    }
}

extern "C" void kernel_launch(void* const* d_in, const int* in_sizes, int n_in,
                              void* d_out, int out_size, void* d_ws, size_t ws_size,
                              hipStream_t stream)
{
    const float* af = (const float*)d_in[0];
    const float* vf = (const float*)d_in[1];
    const int*   la = (const int*)d_in[2];
    const int*   lv = (const int*)d_in[3];
    float* out = (float*)d_out;

    char* ws = (char*)d_ws;
    unsigned char* aB = (unsigned char*)ws;                            // 2 MiB (MX fp8 fragment order)
    unsigned char* vB = (unsigned char*)(ws + 2ull * 1024 * 1024);     // 2 MiB
    float* rowPart   = (float*)(ws +  4ull * 1024 * 1024);             // 4 MiB [64][8192][2]
    float* colPart   = (float*)(ws +  8ull * 1024 * 1024);             // 4 MiB [64][8192][2]
    float* glob      = (float*)(ws + 12ull * 1024 * 1024);             // sums + counters

    normalize_kernel<<<1024, 256, 0, stream>>>(af, vf, aB, vB, glob);
    gemm_loss_kernel<<<TOTB, 256, 0, stream>>>(aB, vB, la, lv, rowPart, colPart, glob, out);
}

// Round 12
// 130.904 us; speedup vs baseline: 2.4365x; 2.1806x over previous
//
#include <hip/hip_runtime.h>

// Problem constants (B=32, N=256, D=256 -> M=8192)
#define M_ROWS 8192
#define D_DIM  256
#define TOTB   4096               // gemm blocks (128x128 tile each)

// Fold 1/TEMP * log2(e) into normalization: acc = log2(e)*sim/TEMP, e = exp2(acc)
#define ALPHA  4.53982478f        // sqrt(log2(e)/0.07)

// MX fp8 fragment-order layout (for mfma_scale 16x16x128):
//   per (tile16, kb) fragment = 2048 B: lane (quad*16+l16) holds 32 B =
//   row (tile16*16 + l16), k = kb*128 + quad*32 + [0..31]   (32 x e4m3)
//   tile16 stride = 4096 B (2 kb blocks); full matrix = 512 tiles = 2 MiB.

typedef __attribute__((ext_vector_type(4))) float  floatx4;  // MFMA C/D
typedef __attribute__((ext_vector_type(8))) int    intx8;    // MFMA A/B (32 B)

__device__ inline unsigned short f2bf(float f) {
    union { float f; unsigned int u; } v; v.f = f;
    unsigned int u = v.u;
    u = (u + 0x7fffu + ((u >> 16) & 1u)) >> 16;   // RNE
    return (unsigned short)u;
}

__device__ inline float bf2f(unsigned short b) {
    union { unsigned int u; float f; } v; v.u = (unsigned int)b << 16;
    return v.f;
}

__device__ inline float fast_exp2(float x) {
#if __has_builtin(__builtin_amdgcn_exp2f)
    return __builtin_amdgcn_exp2f(x);
#else
    return exp2f(x);
#endif
}

// Kernel 1: L2-normalize 16 rows per block, scale by ALPHA, emit fp8 e4m3 in
// MX fragment order via padded LDS transpose. Block 0 zeroes glob
// ([0..3]=sums, int[4]=finalize counter).
__global__ __launch_bounds__(256) void normalize_kernel(
    const float* __restrict__ af, const float* __restrict__ vf,
    unsigned char* __restrict__ aB, unsigned char* __restrict__ vB,
    float* __restrict__ glob)
{
    __shared__ unsigned short tileS[16 * 264];   // 8.25 KB

    if (blockIdx.x == 0) {
        if (threadIdx.x < 4) glob[threadIdx.x] = 0.f;
        if (threadIdx.x == 4) ((int*)glob)[4] = 0;
    }

    const int b = blockIdx.x;            // 0..1023
    const bool isA = b < 512;
    const int T = isA ? b : b - 512;     // tile16 index 0..511
    const float* src = (isA ? af : vf) + (size_t)T * 16 * D_DIM;
    unsigned char* dst = (isA ? aB : vB) + (size_t)T * 4096;

    const int t = threadIdx.x;
    const int row = t >> 4, c = t & 15;  // 16 threads per row, 16 elems each

    const float* p = src + row * D_DIM + c * 16;
    float4 x0 = ((const float4*)p)[0], x1 = ((const float4*)p)[1];
    float4 x2 = ((const float4*)p)[2], x3 = ((const float4*)p)[3];
    float ss = x0.x*x0.x + x0.y*x0.y + x0.z*x0.z + x0.w*x0.w
             + x1.x*x1.x + x1.y*x1.y + x1.z*x1.z + x1.w*x1.w
             + x2.x*x2.x + x2.y*x2.y + x2.z*x2.z + x2.w*x2.w
             + x3.x*x3.x + x3.y*x3.y + x3.z*x3.z + x3.w*x3.w;
    #pragma unroll
    for (int m = 1; m < 16; m <<= 1) ss += __shfl_xor(ss, m, 64);
    float scale = ALPHA / fmaxf(sqrtf(ss), 1e-12f);

    unsigned short* q = tileS + row * 264 + c * 16;
    ushort4 o0, o1, o2, o3;
    o0.x = f2bf(x0.x*scale); o0.y = f2bf(x0.y*scale); o0.z = f2bf(x0.z*scale); o0.w = f2bf(x0.w*scale);
    o1.x = f2bf(x1.x*scale); o1.y = f2bf(x1.y*scale); o1.z = f2bf(x1.z*scale); o1.w = f2bf(x1.w*scale);
    o2.x = f2bf(x2.x*scale); o2.y = f2bf(x2.y*scale); o2.z = f2bf(x2.z*scale); o2.w = f2bf(x2.w*scale);
    o3.x = f2bf(x3.x*scale); o3.y = f2bf(x3.y*scale); o3.z = f2bf(x3.z*scale); o3.w = f2bf(x3.w*scale);
    ((ushort4*)q)[0] = o0; ((ushort4*)q)[1] = o1;
    ((ushort4*)q)[2] = o2; ((ushort4*)q)[3] = o3;
    __syncthreads();

    // phase 2: thread t emits 16 B of the MX fragment layout (byte off = t*16):
    // kb = t>>7, r = t&127, lane = r>>1, half = r&1;
    // source = LDS row (lane&15), k = kb*128 + (lane>>4)*32 + half*16 .. +15
    {
        const int kb = t >> 7, r = t & 127;
        const int ln = r >> 1, half = r & 1;
        const int quad = ln >> 4, l16 = ln & 15;
        const unsigned short* rp = &tileS[l16 * 264 + kb * 128 + quad * 32 + half * 16];
        int4 outv;
        int* op = (int*)&outv;
        #pragma unroll
        for (int g = 0; g < 4; ++g) {
            float f0 = bf2f(rp[g*4+0]), f1 = bf2f(rp[g*4+1]);
            float f2 = bf2f(rp[g*4+2]), f3 = bf2f(rp[g*4+3]);
            int pk = __builtin_amdgcn_cvt_pk_fp8_f32(f0, f1, 0, false);
            pk     = __builtin_amdgcn_cvt_pk_fp8_f32(f2, f3, pk, true);
            op[g] = pk;
        }
        *(int4*)(dst + (size_t)t * 16) = outv;
    }
}

// Kernel 2: MX fp8 GEMM (acc = log2e*sim/T) + exp2 + (total,class1) partials.
// NO fences, NO tail protocol (R11 lesson: per-block device fences serialize
// at the TCC). Block 256 = 4 waves; block tile 128x128 (supertile swizzle);
// wave quadrant 64x64: acc[4][4] (64 AGPR), 2 K=128 steps, unit E8M0 scales.
__global__ __launch_bounds__(256, 3) void gemm_loss_kernel(
    const unsigned char* __restrict__ aB, const unsigned char* __restrict__ vB,
    const int* __restrict__ la, const int* __restrict__ lv,
    float* __restrict__ rowPart, float* __restrict__ colPart)
{
    const int tid  = threadIdx.x;
    const int wave = tid >> 6, lane = tid & 63;
    const int quad = lane >> 4, l16 = lane & 15;
    const int rowhalf = wave >> 1, colhalf = wave & 1;

    // supertile swizzle: 16 supers x 256 inner -> 16x16 tile regions (L2 locality)
    const int super = blockIdx.x >> 8;          // 0..15
    const int inner = blockIdx.x & 255;
    const int bx = (super & 3) * 16 + (inner & 15);    // 0..63 (i-tile)
    const int by = (super >> 2) * 16 + (inner >> 4);   // 0..63 (j-tile)
    const int i0 = bx * 128, j0 = by * 128;

    // fragment bases: tile16 stride 4096 B, kb stride 2048 B, lane*32 B
    const unsigned char* Abase = aB + (size_t)(bx * 8 + rowhalf * 4) * 4096 + (size_t)lane * 32;
    const unsigned char* Vbase = vB + (size_t)(by * 8 + colhalf * 4) * 4096 + (size_t)lane * 32;

    floatx4 acc[4][4] = {};

    #pragma unroll
    for (int kb = 0; kb < 2; ++kb) {            // two K=128 steps (K=256)
        intx8 afr[4], bfr[4];
        #pragma unroll
        for (int it = 0; it < 4; ++it) {
            const unsigned char* p = Abase + it * 4096 + kb * 2048;
            ((int4*)&afr[it])[0] = *(const int4*)p;
            ((int4*)&afr[it])[1] = *(const int4*)(p + 16);
        }
        #pragma unroll
        for (int jt = 0; jt < 4; ++jt) {
            const unsigned char* p = Vbase + jt * 4096 + kb * 2048;
            ((int4*)&bfr[jt])[0] = *(const int4*)p;
            ((int4*)&bfr[jt])[1] = *(const int4*)(p + 16);
        }
        #pragma unroll
        for (int it = 0; it < 4; ++it)
            #pragma unroll
            for (int jt = 0; jt < 4; ++jt)
                acc[it][jt] = __builtin_amdgcn_mfma_scale_f32_16x16x128_f8f6f4(
                    afr[it], bfr[jt], acc[it][jt],
                    0 /*cbsz: fp8*/, 0 /*blgp: fp8*/,
                    0, 0x7f7f7f7f,   /* scale A = 1.0 (E8M0 127) */
                    0, 0x7f7f7f7f);  /* scale B = 1.0 */
    }

    // ---- epilogue: exp2 + (total, class1); C/D: col = l16, row = quad*4 + r
    float maf[4][4];
    #pragma unroll
    for (int it = 0; it < 4; ++it)
        #pragma unroll
        for (int r = 0; r < 4; ++r)
            maf[it][r] = (float)la[i0 + rowhalf * 64 + it * 16 + quad * 4 + r];
    float mvf[4];
    #pragma unroll
    for (int jt = 0; jt < 4; ++jt)
        mvf[jt] = (float)lv[j0 + colhalf * 64 + jt * 16 + l16];

    float rT[4][4] = {}, r1[4][4] = {};
    float cT[4] = {}, c1[4] = {};
    #pragma unroll
    for (int it = 0; it < 4; ++it) {
        #pragma unroll
        for (int jt = 0; jt < 4; ++jt) {
            #pragma unroll
            for (int r = 0; r < 4; ++r) {
                float e = fast_exp2(acc[it][jt][r]);
                rT[it][r] += e;
                r1[it][r] = fmaf(mvf[jt], e, r1[it][r]);
                cT[jt] += e;
                c1[jt] = fmaf(maf[it][r], e, c1[jt]);
            }
        }
    }

    __shared__ float rowS[2][128][2];   // [colhalf][row][cls] 2 KB
    __shared__ float colS[2][128][2];   // [rowhalf][col][cls] 2 KB

    // row sums: reduce over the quad's 16 lanes, stage per col-half
    #pragma unroll
    for (int it = 0; it < 4; ++it) {
        #pragma unroll
        for (int r = 0; r < 4; ++r) {
            float s0 = rT[it][r], s1 = r1[it][r];
            #pragma unroll
            for (int m = 1; m < 16; m <<= 1) {
                s0 += __shfl_xor(s0, m, 64);
                s1 += __shfl_xor(s1, m, 64);
            }
            if (l16 == 0) {
                int rl = rowhalf * 64 + it * 16 + quad * 4 + r;   // 0..127
                rowS[colhalf][rl][0] = s0;
                rowS[colhalf][rl][1] = s1;
            }
        }
    }
    // col sums: reduce over quads (register-only), stage per row-half
    #pragma unroll
    for (int jt = 0; jt < 4; ++jt) {
        float t0 = cT[jt], t1 = c1[jt];
        t0 += __shfl_xor(t0, 16, 64); t0 += __shfl_xor(t0, 32, 64);
        t1 += __shfl_xor(t1, 16, 64); t1 += __shfl_xor(t1, 32, 64);
        if (quad == 0) {
            int cl = colhalf * 64 + jt * 16 + l16;                // 0..127
            colS[rowhalf][cl][0] = t0;
            colS[rowhalf][cl][1] = t1;
        }
    }
    __syncthreads();

    // combine halves, coalesced per-block partial writes (256 floats each)
    {
        const int rl  = tid >> 1;      // 0..127
        const int cls = tid & 1;
        rowPart[((size_t)by * M_ROWS + i0 + rl) * 2 + cls] =
            rowS[0][rl][cls] + rowS[1][rl][cls];
        colPart[((size_t)bx * M_ROWS + j0 + rl) * 2 + cls] =
            colS[0][rl][cls] + colS[1][rl][cls];
    }
}

// Kernel 3: reduce partials over 64 slabs, per-row/col log terms, merged
// finalize via atomic counter (only 64 blocks -> fences are cheap here).
// Blocks 0..31 = audio(rows), 32..63 = visual(cols).
// glob: [sumA, cntA, sumV, cntV, (int)counter] - zeroed by normalize block 0.
__global__ __launch_bounds__(256) void reduce_kernel(
    const float* __restrict__ rowPart, const float* __restrict__ colPart,
    const int* __restrict__ la, const int* __restrict__ lv,
    float* __restrict__ glob, float* __restrict__ out)
{
    const int bid = blockIdx.x;
    const bool aside = bid < 32;
    const int idx = (aside ? bid : bid - 32) * 256 + threadIdx.x;   // row or col index
    const float* part = aside ? rowPart : colPart;
    const int* lab = aside ? la : lv;

    float tot = 0.f, c1 = 0.f;
    #pragma unroll 4
    for (int b = 0; b < 64; ++b) {
        float2 p = *(const float2*)(part + ((size_t)b * M_ROWS + idx) * 2);
        tot += p.x; c1 += p.y;
    }
    float num = lab[idx] ? c1 : 0.1f * (tot - c1);
    float lg = 0.f, cnt = 0.f;
    if (num > 0.f) { lg = logf((num + 1e-8f) / (tot + 1e-8f)); cnt = 1.f; }

    #pragma unroll
    for (int m = 1; m < 64; m <<= 1) {
        lg  += __shfl_xor(lg,  m, 64);
        cnt += __shfl_xor(cnt, m, 64);
    }
    __shared__ float red[4][2];
    const int w = threadIdx.x >> 6, ln = threadIdx.x & 63;
    if (ln == 0) { red[w][0] = lg; red[w][1] = cnt; }
    __syncthreads();
    if (threadIdx.x == 0) {
        float slg  = red[0][0] + red[1][0] + red[2][0] + red[3][0];
        float scnt = red[0][1] + red[1][1] + red[2][1] + red[3][1];
        float* base = glob + (aside ? 0 : 2);
        atomicAdd(&base[0], slg);
        atomicAdd(&base[1], scnt);
        __threadfence();
        int old = atomicAdd((int*)glob + 4, 1);
        if (old == 63) {
            __threadfence();
            float sA = atomicAdd(&glob[0], 0.f);
            float cA = atomicAdd(&glob[1], 0.f);
            float sV = atomicAdd(&glob[2], 0.f);
            float cV = atomicAdd(&glob[3], 0.f);
            float lossA = -sA / fmaxf(cA, 1.f);
            float lossV = -sV / fmaxf(cV, 1.f);
            out[0] = 0.5f * (lossA + lossV);
        }
    }
}

extern "C" void kernel_launch(void* const* d_in, const int* in_sizes, int n_in,
                              void* d_out, int out_size, void* d_ws, size_t ws_size,
                              hipStream_t stream)
{
    const float* af = (const float*)d_in[0];
    const float* vf = (const float*)d_in[1];
    const int*   la = (const int*)d_in[2];
    const int*   lv = (const int*)d_in[3];
    float* out = (float*)d_out;

    char* ws = (char*)d_ws;
    unsigned char* aB = (unsigned char*)ws;                            // 2 MiB (MX fp8 fragment order)
    unsigned char* vB = (unsigned char*)(ws + 2ull * 1024 * 1024);     // 2 MiB
    float* rowPart   = (float*)(ws +  4ull * 1024 * 1024);             // 4 MiB [64][8192][2]
    float* colPart   = (float*)(ws +  8ull * 1024 * 1024);             // 4 MiB [64][8192][2]
    float* glob      = (float*)(ws + 12ull * 1024 * 1024);             // sums + counter

    normalize_kernel<<<1024, 256, 0, stream>>>(af, vf, aB, vB, glob);
    gemm_loss_kernel<<<TOTB, 256, 0, stream>>>(aB, vB, la, lv, rowPart, colPart);
    reduce_kernel<<<64, 256, 0, stream>>>(rowPart, colPart, la, lv, glob, out);
}